// Round 13
// baseline (183.484 us; speedup 1.0000x reference)
//
#include <hip/hip_runtime.h>
#include <hip/hip_bf16.h>
#include <hip/hip_fp16.h>
#include <cstddef>
#include <cstdint>

#define BIGV 10000000.0f
#define WPV  1.0f

#define BATCH 8
#define T1N 256
#define T2N 1024
#define CN 128
#define DN 1279          // T1+T2-1

#define FLAG_MAGIC 0x600D0000

typedef __attribute__((ext_vector_type(2))) _Float16 half2v;

// ---------------------------------------------------------------------------
// Kernel 1 (R28, unchanged — delivered 133.4 total): cost 32(d)x64(j) tile,
// 40.7KB LDS -> 4 blocks/CU.
// ---------------------------------------------------------------------------
__global__ __launch_bounds__(256) void cost_kernel(const float* __restrict__ A,
                                                   const float* __restrict__ Bf,
                                                   const int* __restrict__ lenA,
                                                   const int* __restrict__ lenB,
                                                   float* __restrict__ sk) {
    __shared__ char As[64 * 256];     // 64 j-rows x 128 f16 ch (16,384 B)
    __shared__ char Bs[95 * 256];     // 95 rows x 128 f16 ch   (24,320 B)

    const int b  = blockIdx.z;
    const int d0 = blockIdx.y * 32;
    const int j0 = blockIdx.x * 64;
    const int tid = threadIdx.x;

    const int dEnd = lenA[b] + lenB[b] - 2;
    if (d0 > dEnd) return;            // rows never consumed

    const float* Ab = A  + (size_t)b * T1N * CN;
    const float* Bb = Bf + (size_t)b * T2N * CN;

    const int tj = tid & 15;
    const int td = tid >> 4;
    const int brow0 = td - tj + 63;   // in [48,78]; rows brow0+16(m-3) in [0,94]
    const int rbase = d0 - j0 - 63;

    // swizzled byte offset: row stride 256B; 16B groups rotated by row
#define SWB(row, g) (((row) << 8) + ((((g) + (row)) & 15) << 4))

    // ---- stage A: 64 rows x 32 f32-quads = 2048 -> 8 per thread ----
    #pragma unroll
    for (int i = 0; i < 8; ++i) {
        int idx = tid + i * 256;
        int row = idx >> 5;
        int q   = idx & 31;               // channels 4q..4q+3
        float4 f = *(const float4*)(Ab + (size_t)(j0 + row) * CN + (q << 2));
        half2v h0 = { (_Float16)f.x, (_Float16)f.y };
        half2v h1 = { (_Float16)f.z, (_Float16)f.w };
        char* dst = As + SWB(row, q >> 1) + ((q & 1) << 3);
        ((uint32_t*)dst)[0] = __builtin_bit_cast(uint32_t, h0);
        ((uint32_t*)dst)[1] = __builtin_bit_cast(uint32_t, h1);
    }
    // ---- stage B: 95 rows x 32 quads = 3040 -> 12 per thread (guarded) ----
    #pragma unroll
    for (int i = 0; i < 12; ++i) {
        int idx = tid + i * 256;
        if (idx < 3040) {
            int row = idx >> 5;
            int q   = idx & 31;
            int gr = rbase + row;
            gr = gr < 0 ? 0 : (gr > T2N - 1 ? T2N - 1 : gr);
            float4 f = *(const float4*)(Bb + (size_t)gr * CN + (q << 2));
            half2v h0 = { (_Float16)f.x, (_Float16)f.y };
            half2v h1 = { (_Float16)f.z, (_Float16)f.w };
            char* dst = Bs + SWB(row, q >> 1) + ((q & 1) << 3);
            ((uint32_t*)dst)[0] = __builtin_bit_cast(uint32_t, h0);
            ((uint32_t*)dst)[1] = __builtin_bit_cast(uint32_t, h1);
        }
    }
    __syncthreads();

    float acc[2][4];
    #pragma unroll
    for (int i = 0; i < 2; ++i)
        #pragma unroll
        for (int j = 0; j < 4; ++j) acc[i][j] = 0.0f;

    const half2v one2 = { (_Float16)1.0f, (_Float16)1.0f };

    for (int g = 0; g < 16; ++g) {        // 8 channels per group
        uint4 a4[4], bv[5];
        #pragma unroll
        for (int ji = 0; ji < 4; ++ji) {
            int row = tj + 16 * ji;
            a4[ji] = *(const uint4*)(As + SWB(row, g));
        }
        #pragma unroll
        for (int m = 0; m < 5; ++m) {
            int row = brow0 + 16 * (m - 3);
            bv[m] = *(const uint4*)(Bs + SWB(row, g));
        }
        #pragma unroll
        for (int dk = 0; dk < 2; ++dk) {
            #pragma unroll
            for (int ji = 0; ji < 4; ++ji) {
                uint4 au = a4[ji];
                uint4 bu = bv[dk - ji + 3];
                float a = acc[dk][ji];
                #pragma unroll
                for (int w = 0; w < 4; ++w) {
                    uint32_t ua = (&au.x)[w];
                    uint32_t ub = (&bu.x)[w];
                    half2v d2 = __builtin_bit_cast(half2v, ua)
                              - __builtin_bit_cast(half2v, ub);
                    uint32_t du = __builtin_bit_cast(uint32_t, d2) & 0x7FFF7FFFu;
#if __has_builtin(__builtin_amdgcn_fdot2)
                    a = __builtin_amdgcn_fdot2(__builtin_bit_cast(half2v, du),
                                               one2, a, false);
#else
                    half2v ad = __builtin_bit_cast(half2v, du);
                    a += (float)ad.x + (float)ad.y;
#endif
                }
                acc[dk][ji] = a;
            }
        }
    }
#undef SWB

    #pragma unroll
    for (int dk = 0; dk < 2; ++dk) {
        int d = d0 + td + 16 * dk;
        if (d < DN) {
            size_t rowoff = ((size_t)b * DN + d) * T1N;
            #pragma unroll
            for (int ji = 0; ji < 4; ++ji) {
                int j = j0 + tj + 16 * ji;
                sk[rowoff + j] = acc[dk][ji] * (1.0f / 128.0f);
            }
        }
    }
}

// ---------------------------------------------------------------------------
// Kernel 2 (R29): dp DUAL-CHAIN — two independent batches per wave, 4 blocks.
// Discriminating experiment for dp's structure-invariant ~95cy/step:
//  H1 (dependency stall @ full clock): interleaving chain B's independent
//     instructions fills chain A's stall slots -> ~64cy/row-pair -> dp 34-40us.
//  H2 (clock throttle at 3% util): issue-bound at low clock -> dp 65-80us
//     (then revert + declare ceiling).
// Batches paired by sorted dEnd (uniform 8-elem insertion sort) to minimize
// the longer chain's solo tail. Per-chain math = R21's proven DP_STEP
// (absmax 0.0); shorter chain tails + solo remainder reuse proven guard code.
// Single block buffer per chain, reload row for block k+1 after consumption
// (dp is L2-hot: R11/R12 replays FETCH=544B at identical speed).
// ---------------------------------------------------------------------------
__device__ __forceinline__ float min3f(float a, float b, float c) {
    float d;
    asm("v_min3_f32 %0, %1, %2, %3" : "=v"(d) : "v"(a), "v"(b), "v"(c));
    return d;
}

__global__ __launch_bounds__(64, 1) void dp_dual_kernel(const float* __restrict__ sk,
                                                        const int* __restrict__ lenA,
                                                        const int* __restrict__ lenB,
                                                        float* __restrict__ partials,
                                                        int* __restrict__ flags,
                                                        float* __restrict__ out) {
    const int blk = blockIdx.x;           // 0..3
    const int L = threadIdx.x;            // 0..63, columns 4L..4L+3

    // ---- pair batches by sorted dEnd (uniform scalar; one-time) ----
    int ds[8], is[8];
    for (int i = 0; i < 8; ++i) { ds[i] = lenA[i] + lenB[i] - 2; is[i] = i; }
    for (int i = 1; i < 8; ++i) {
        int dv = ds[i], iv = is[i];
        int j = i - 1;
        while (j >= 0 && ds[j] > dv) { ds[j+1] = ds[j]; is[j+1] = is[j]; --j; }
        ds[j+1] = dv; is[j+1] = iv;
    }
    const int bA    = __builtin_amdgcn_readfirstlane(is[2*blk]);
    const int bB    = __builtin_amdgcn_readfirstlane(is[2*blk+1]);
    const int dEndA = __builtin_amdgcn_readfirstlane(ds[2*blk]);
    const int dEndB = __builtin_amdgcn_readfirstlane(ds[2*blk+1]);   // >= dEndA
    const int laA   = __builtin_amdgcn_readfirstlane(lenA[bA]);
    const int laB   = __builtin_amdgcn_readfirstlane(lenB ? lenA[bB] : 0);
    const int kLastA = dEndA >> 4;        // <= kLastB
    const int kLastB = dEndB >> 4;

    const char* lanepA = (const char*)(sk + (size_t)bA * DN * T1N) + (L << 4);
    const char* lanepB = (const char*)(sk + (size_t)bB * DN * T1N) + (L << 4);

    // per-chain DP state
    float v1a_0 = BIGV, v1a_1 = BIGV, v1a_2 = BIGV, v1a_3 = BIGV;
    float v2a_0 = BIGV, v2a_1 = BIGV, v2a_2 = BIGV, v2a_3 = BIGV;
    float v1b_0 = BIGV, v1b_1 = BIGV, v1b_2 = BIGV, v1b_3 = BIGV;
    float v2b_0 = BIGV, v2b_1 = BIGV, v2b_2 = BIGV, v2b_3 = BIGV;
    float ppa = (L == 0) ? 0.0f : BIGV;
    float ppb = (L == 0) ? 0.0f : BIGV;

    float4 CA0, CA1, CA2, CA3, CA4, CA5, CA6, CA7,
           CA8, CA9, CA10, CA11, CA12, CA13, CA14, CA15;
    float4 CB0, CB1, CB2, CB3, CB4, CB5, CB6, CB7,
           CB8, CB9, CB10, CB11, CB12, CB13, CB14, CB15;

#define SHFL_UP1(SRC)                                                       \
    __int_as_float(__builtin_amdgcn_update_dpp(                             \
        __float_as_int(BIGV), __float_as_int(SRC),                          \
        0x138 /* wave_shr:1 */, 0xF, 0xF, false))

    // clamp row to own dEnd (always-written sk region; proven pattern)
#define LOAD1X(DST, PFX, KB, R) do {                                        \
        int row_ = ((KB) << 4) + (R);                                       \
        row_ = row_ > dEnd##PFX ? dEnd##PFX : row_;                         \
        DST = *(const float4*)(lanep##PFX + (size_t)row_ * (T1N * 4));      \
    } while (0)

    // P in {a,b}: one DP step on chain P (R21-proven math)
#define DP_STEPX(C4, P) do {                                                \
        float4 c_ = (C4);                                                   \
        float p1_ = SHFL_UP1(v1##P##_3);                                    \
        float w0_ = v1##P##_0 + WPV, w1_ = v1##P##_1 + WPV;                 \
        float w2_ = v1##P##_2 + WPV, w3_ = v1##P##_3 + WPV;                 \
        float wp_ = p1_ + WPV;                                              \
        float n0_ = c_.x + min3f(pp##P, w0_, wp_);                          \
        float n1_ = c_.y + min3f(v2##P##_0, w1_, w0_);                      \
        float n2_ = c_.z + min3f(v2##P##_1, w2_, w1_);                      \
        float n3_ = c_.w + min3f(v2##P##_2, w3_, w2_);                      \
        pp##P = p1_;                                                        \
        v2##P##_0 = v1##P##_0; v2##P##_1 = v1##P##_1;                       \
        v2##P##_2 = v1##P##_2; v2##P##_3 = v1##P##_3;                       \
        v1##P##_0 = n0_; v1##P##_1 = n1_; v1##P##_2 = n2_; v1##P##_3 = n3_; \
    } while (0)

#define DP_STEPX_G(C4, P, R, REM) do {                                      \
        float4 c_ = (C4);                                                   \
        float p1_ = SHFL_UP1(v1##P##_3);                                    \
        float w0_ = v1##P##_0 + WPV, w1_ = v1##P##_1 + WPV;                 \
        float w2_ = v1##P##_2 + WPV, w3_ = v1##P##_3 + WPV;                 \
        float wp_ = p1_ + WPV;                                              \
        float n0_ = c_.x + min3f(pp##P, w0_, wp_);                          \
        float n1_ = c_.y + min3f(v2##P##_0, w1_, w0_);                      \
        float n2_ = c_.z + min3f(v2##P##_1, w2_, w1_);                      \
        float n3_ = c_.w + min3f(v2##P##_2, w3_, w2_);                      \
        if ((R) <= (REM)) {                                                 \
            pp##P = p1_;                                                    \
            v2##P##_0 = v1##P##_0; v2##P##_1 = v1##P##_1;                   \
            v2##P##_2 = v1##P##_2; v2##P##_3 = v1##P##_3;                   \
            v1##P##_0 = n0_; v1##P##_1 = n1_;                               \
            v1##P##_2 = n2_; v1##P##_3 = n3_;                               \
        }                                                                   \
    } while (0)

    // one interleaved row: step A, reload A for k+1; step B, reload B for k+1
#define DROW(R) do {                                                        \
        DP_STEPX(CA##R, a); LOAD1X(CA##R, A, k + 1, R);                     \
        DP_STEPX(CB##R, b); LOAD1X(CB##R, B, k + 1, R);                     \
    } while (0)

#define BROW(R) do {                                                        \
        DP_STEPX(CB##R, b); LOAD1X(CB##R, B, k2 + 1, R);                    \
    } while (0)

    // prologue: block 0 for both chains
    LOAD1X(CA0, A, 0, 0);   LOAD1X(CB0, B, 0, 0);
    LOAD1X(CA1, A, 0, 1);   LOAD1X(CB1, B, 0, 1);
    LOAD1X(CA2, A, 0, 2);   LOAD1X(CB2, B, 0, 2);
    LOAD1X(CA3, A, 0, 3);   LOAD1X(CB3, B, 0, 3);
    LOAD1X(CA4, A, 0, 4);   LOAD1X(CB4, B, 0, 4);
    LOAD1X(CA5, A, 0, 5);   LOAD1X(CB5, B, 0, 5);
    LOAD1X(CA6, A, 0, 6);   LOAD1X(CB6, B, 0, 6);
    LOAD1X(CA7, A, 0, 7);   LOAD1X(CB7, B, 0, 7);
    LOAD1X(CA8, A, 0, 8);   LOAD1X(CB8, B, 0, 8);
    LOAD1X(CA9, A, 0, 9);   LOAD1X(CB9, B, 0, 9);
    LOAD1X(CA10, A, 0, 10); LOAD1X(CB10, B, 0, 10);
    LOAD1X(CA11, A, 0, 11); LOAD1X(CB11, B, 0, 11);
    LOAD1X(CA12, A, 0, 12); LOAD1X(CB12, B, 0, 12);
    LOAD1X(CA13, A, 0, 13); LOAD1X(CB13, B, 0, 13);
    LOAD1X(CA14, A, 0, 14); LOAD1X(CB14, B, 0, 14);
    LOAD1X(CA15, A, 0, 15); LOAD1X(CB15, B, 0, 15);

    // dual main loop: full blocks 0..kLastA-1 for BOTH chains (kLastA >= 39)
    for (int k = 0; k < kLastA; ++k) {
        DROW(0);  DROW(1);  DROW(2);  DROW(3);
        DROW(4);  DROW(5);  DROW(6);  DROW(7);
        DROW(8);  DROW(9);  DROW(10); DROW(11);
        DROW(12); DROW(13); DROW(14); DROW(15);
    }
    // buffers now hold block kLastA for both chains.

    // chain A guarded tail (block kLastA)
    {
        const int remA = dEndA & 15;
        DP_STEPX_G(CA0, a, 0, remA);   DP_STEPX_G(CA1, a, 1, remA);
        DP_STEPX_G(CA2, a, 2, remA);   DP_STEPX_G(CA3, a, 3, remA);
        DP_STEPX_G(CA4, a, 4, remA);   DP_STEPX_G(CA5, a, 5, remA);
        DP_STEPX_G(CA6, a, 6, remA);   DP_STEPX_G(CA7, a, 7, remA);
        DP_STEPX_G(CA8, a, 8, remA);   DP_STEPX_G(CA9, a, 9, remA);
        DP_STEPX_G(CA10, a, 10, remA); DP_STEPX_G(CA11, a, 11, remA);
        DP_STEPX_G(CA12, a, 12, remA); DP_STEPX_G(CA13, a, 13, remA);
        DP_STEPX_G(CA14, a, 14, remA); DP_STEPX_G(CA15, a, 15, remA);
    }
    // publish chain A
    {
        const int tcap = laA - 1;
        if (L == (tcap >> 2)) {
            const int kk = tcap & 3;
            float r = v1a_0;
            if (kk == 1) r = v1a_1;
            else if (kk == 2) r = v1a_2;
            else if (kk == 3) r = v1a_3;
            partials[bA] = r;
            __threadfence();
            __hip_atomic_store(&flags[bA], FLAG_MAGIC + bA,
                               __ATOMIC_RELEASE, __HIP_MEMORY_SCOPE_AGENT);
        }
    }

    // chain B solo remainder: full blocks kLastA..kLastB-1
    for (int k2 = kLastA; k2 < kLastB; ++k2) {
        BROW(0);  BROW(1);  BROW(2);  BROW(3);
        BROW(4);  BROW(5);  BROW(6);  BROW(7);
        BROW(8);  BROW(9);  BROW(10); BROW(11);
        BROW(12); BROW(13); BROW(14); BROW(15);
    }
    // chain B guarded tail (block kLastB)
    {
        const int remB = dEndB & 15;
        DP_STEPX_G(CB0, b, 0, remB);   DP_STEPX_G(CB1, b, 1, remB);
        DP_STEPX_G(CB2, b, 2, remB);   DP_STEPX_G(CB3, b, 3, remB);
        DP_STEPX_G(CB4, b, 4, remB);   DP_STEPX_G(CB5, b, 5, remB);
        DP_STEPX_G(CB6, b, 6, remB);   DP_STEPX_G(CB7, b, 7, remB);
        DP_STEPX_G(CB8, b, 8, remB);   DP_STEPX_G(CB9, b, 9, remB);
        DP_STEPX_G(CB10, b, 10, remB); DP_STEPX_G(CB11, b, 11, remB);
        DP_STEPX_G(CB12, b, 12, remB); DP_STEPX_G(CB13, b, 13, remB);
        DP_STEPX_G(CB14, b, 14, remB); DP_STEPX_G(CB15, b, 15, remB);
    }
    // publish chain B
    {
        const int tcap = laB - 1;
        if (L == (tcap >> 2)) {
            const int kk = tcap & 3;
            float r = v1b_0;
            if (kk == 1) r = v1b_1;
            else if (kk == 2) r = v1b_2;
            else if (kk == 3) r = v1b_3;
            partials[bB] = r;
            __threadfence();
            __hip_atomic_store(&flags[bB], FLAG_MAGIC + bB,
                               __ATOMIC_RELEASE, __HIP_MEMORY_SCOPE_AGENT);
        }
    }

    // block 0: gather all 8 partials and write the final sum
    if (blk == 0 && L == 0) {
        float s = 0.0f;
        for (int i = 0; i < BATCH; ++i) {
            while (__hip_atomic_load(&flags[i], __ATOMIC_ACQUIRE,
                                     __HIP_MEMORY_SCOPE_AGENT) != FLAG_MAGIC + i)
                __builtin_amdgcn_s_sleep(2);
            s += __hip_atomic_load(&partials[i], __ATOMIC_RELAXED,
                                   __HIP_MEMORY_SCOPE_AGENT);
        }
        out[0] = s;
    }
#undef BROW
#undef DROW
#undef DP_STEPX_G
#undef DP_STEPX
#undef LOAD1X
#undef SHFL_UP1
}

extern "C" void kernel_launch(void* const* d_in, const int* in_sizes, int n_in,
                              void* d_out, int out_size, void* d_ws, size_t ws_size,
                              hipStream_t stream) {
    const float* feaA = (const float*)d_in[0];
    const int*   lenA = (const int*)d_in[1];
    const float* feaB = (const float*)d_in[2];
    const int*   lenB = (const int*)d_in[3];

    float* sk = (float*)d_ws;                                   // 8*1279*256*4 B
    float* partials = (float*)((char*)d_ws + (size_t)BATCH * DN * T1N * sizeof(float));
    int*   flags    = (int*)(partials + BATCH);

    cost_kernel<<<dim3(T1N / 64, (DN + 31) / 32, BATCH), 256, 0, stream>>>(feaA, feaB, lenA, lenB, sk);
    dp_dual_kernel<<<4, 64, 0, stream>>>(sk, lenA, lenB, partials, flags, (float*)d_out);
}

// Round 14
// 137.459 us; speedup vs baseline: 1.3348x; 1.3348x over previous
//
#include <hip/hip_runtime.h>
#include <hip/hip_bf16.h>
#include <hip/hip_fp16.h>
#include <cstddef>
#include <cstdint>

#define BIGV 10000000.0f
#define WPV  1.0f

#define BATCH 8
#define T1N 256
#define T2N 1024
#define CN 128
#define DN 1279          // T1+T2-1

#define FLAG_MAGIC 0x600D0000

typedef __attribute__((ext_vector_type(2))) _Float16 half2v;

// ---------------------------------------------------------------------------
// Kernel 1 (R28, proven 133.4 total): cost 32(d)x64(j) tile, 40.7KB LDS
// -> 4 blocks/CU resident.
// ---------------------------------------------------------------------------
__global__ __launch_bounds__(256) void cost_kernel(const float* __restrict__ A,
                                                   const float* __restrict__ Bf,
                                                   const int* __restrict__ lenA,
                                                   const int* __restrict__ lenB,
                                                   float* __restrict__ sk) {
    __shared__ char As[64 * 256];     // 64 j-rows x 128 f16 ch (16,384 B)
    __shared__ char Bs[95 * 256];     // 95 rows x 128 f16 ch   (24,320 B)

    const int b  = blockIdx.z;
    const int d0 = blockIdx.y * 32;
    const int j0 = blockIdx.x * 64;
    const int tid = threadIdx.x;

    const int dEnd = lenA[b] + lenB[b] - 2;
    if (d0 > dEnd) return;            // rows never consumed

    const float* Ab = A  + (size_t)b * T1N * CN;
    const float* Bb = Bf + (size_t)b * T2N * CN;

    const int tj = tid & 15;
    const int td = tid >> 4;
    const int brow0 = td - tj + 63;   // in [48,78]; rows brow0+16(m-3) in [0,94]
    const int rbase = d0 - j0 - 63;

    // swizzled byte offset: row stride 256B; 16B groups rotated by row
#define SWB(row, g) (((row) << 8) + ((((g) + (row)) & 15) << 4))

    // ---- stage A: 64 rows x 32 f32-quads = 2048 -> 8 per thread ----
    #pragma unroll
    for (int i = 0; i < 8; ++i) {
        int idx = tid + i * 256;
        int row = idx >> 5;
        int q   = idx & 31;               // channels 4q..4q+3
        float4 f = *(const float4*)(Ab + (size_t)(j0 + row) * CN + (q << 2));
        half2v h0 = { (_Float16)f.x, (_Float16)f.y };
        half2v h1 = { (_Float16)f.z, (_Float16)f.w };
        char* dst = As + SWB(row, q >> 1) + ((q & 1) << 3);
        ((uint32_t*)dst)[0] = __builtin_bit_cast(uint32_t, h0);
        ((uint32_t*)dst)[1] = __builtin_bit_cast(uint32_t, h1);
    }
    // ---- stage B: 95 rows x 32 quads = 3040 -> 12 per thread (guarded) ----
    #pragma unroll
    for (int i = 0; i < 12; ++i) {
        int idx = tid + i * 256;
        if (idx < 3040) {
            int row = idx >> 5;
            int q   = idx & 31;
            int gr = rbase + row;
            gr = gr < 0 ? 0 : (gr > T2N - 1 ? T2N - 1 : gr);
            float4 f = *(const float4*)(Bb + (size_t)gr * CN + (q << 2));
            half2v h0 = { (_Float16)f.x, (_Float16)f.y };
            half2v h1 = { (_Float16)f.z, (_Float16)f.w };
            char* dst = Bs + SWB(row, q >> 1) + ((q & 1) << 3);
            ((uint32_t*)dst)[0] = __builtin_bit_cast(uint32_t, h0);
            ((uint32_t*)dst)[1] = __builtin_bit_cast(uint32_t, h1);
        }
    }
    __syncthreads();

    float acc[2][4];
    #pragma unroll
    for (int i = 0; i < 2; ++i)
        #pragma unroll
        for (int j = 0; j < 4; ++j) acc[i][j] = 0.0f;

    const half2v one2 = { (_Float16)1.0f, (_Float16)1.0f };

    for (int g = 0; g < 16; ++g) {        // 8 channels per group
        uint4 a4[4], bv[5];
        #pragma unroll
        for (int ji = 0; ji < 4; ++ji) {
            int row = tj + 16 * ji;
            a4[ji] = *(const uint4*)(As + SWB(row, g));
        }
        #pragma unroll
        for (int m = 0; m < 5; ++m) {
            int row = brow0 + 16 * (m - 3);
            bv[m] = *(const uint4*)(Bs + SWB(row, g));
        }
        #pragma unroll
        for (int dk = 0; dk < 2; ++dk) {
            #pragma unroll
            for (int ji = 0; ji < 4; ++ji) {
                uint4 au = a4[ji];
                uint4 bu = bv[dk - ji + 3];
                float a = acc[dk][ji];
                #pragma unroll
                for (int w = 0; w < 4; ++w) {
                    uint32_t ua = (&au.x)[w];
                    uint32_t ub = (&bu.x)[w];
                    half2v d2 = __builtin_bit_cast(half2v, ua)
                              - __builtin_bit_cast(half2v, ub);
                    uint32_t du = __builtin_bit_cast(uint32_t, d2) & 0x7FFF7FFFu;
#if __has_builtin(__builtin_amdgcn_fdot2)
                    a = __builtin_amdgcn_fdot2(__builtin_bit_cast(half2v, du),
                                               one2, a, false);
#else
                    half2v ad = __builtin_bit_cast(half2v, du);
                    a += (float)ad.x + (float)ad.y;
#endif
                }
                acc[dk][ji] = a;
            }
        }
    }
#undef SWB

    #pragma unroll
    for (int dk = 0; dk < 2; ++dk) {
        int d = d0 + td + 16 * dk;
        if (d < DN) {
            size_t rowoff = ((size_t)b * DN + d) * T1N;
            #pragma unroll
            for (int ji = 0; ji < 4; ++ji) {
                int j = j0 + tj + 16 * ji;
                sk[rowoff + j] = acc[dk][ji] * (1.0f / 128.0f);
            }
        }
    }
}

// ---------------------------------------------------------------------------
// Kernel 2 (R21, FROZEN — best measured dp at 49.5-50.4us): self-prefetching
// register double-buffer, interleaved reload, min3-folded step.
// Final dp ledger (7 structures): ring 52.2 / THIS 50.4 / reg-grouped 55.4 /
// LDS-DMA 56.2 / PAIR 54.7 / LDS+PAIR 61.7 / dual-chain 113.7(=2x per-wave
// work, per-wave issue rate IDENTICAL -> ILP benefit ZERO). Conclusion:
// issue-rate-bound at ~4.3cy/instr (clock throttle at 3% chip util +
// in-order overhead); invariant to memory structure, chain length, and ILP.
// ---------------------------------------------------------------------------
__device__ __forceinline__ float min3f(float a, float b, float c) {
    float d;
    asm("v_min3_f32 %0, %1, %2, %3" : "=v"(d) : "v"(a), "v"(b), "v"(c));
    return d;
}

__global__ __launch_bounds__(64, 1) void dp_reg_kernel(const float* __restrict__ sk,
                                                       const int* __restrict__ lenA,
                                                       const int* __restrict__ lenB,
                                                       float* __restrict__ partials,
                                                       int* __restrict__ flags,
                                                       float* __restrict__ out) {
    const int b = blockIdx.x;
    const int L = threadIdx.x;            // 0..63, columns 4L..4L+3

    const int la = __builtin_amdgcn_readfirstlane(lenA[b]);
    const int lb = __builtin_amdgcn_readfirstlane(lenB[b]);
    const int dEnd = la + lb - 2;         // in [638, 1278]
    const int kLast = dEnd >> 4;          // final (possibly partial) 16-row block

    const char* lanep = (const char*)(sk + (size_t)b * DN * T1N) + (L << 4);

    float v1_0 = BIGV, v1_1 = BIGV, v1_2 = BIGV, v1_3 = BIGV;
    float v2_0 = BIGV, v2_1 = BIGV, v2_2 = BIGV, v2_3 = BIGV;
    float p1_prev = (L == 0) ? 0.0f : BIGV;   // pcp0 boundary column

    float4 A0, A1, A2, A3, A4, A5, A6, A7, A8, A9, A10, A11, A12, A13, A14, A15;
    float4 B0, B1, B2, B3, B4, B5, B6, B7, B8, B9, B10, B11, B12, B13, B14, B15;

#define SHFL_UP1(SRC)                                                       \
    __int_as_float(__builtin_amdgcn_update_dpp(                             \
        __float_as_int(BIGV), __float_as_int(SRC),                          \
        0x138 /* wave_shr:1 */, 0xF, 0xF, false))

    // rows > dEnd clamp to dEnd: stays inside the region cost_kernel wrote
    // (tiles with d0 > dEnd are skipped there) and inside sk bounds.
#define LOAD1(DST, KB, R) do {                                              \
        int row_ = ((KB) << 4) + (R);                                       \
        row_ = row_ > dEnd ? dEnd : row_;                                   \
        DST = *(const float4*)(lanep + (size_t)row_ * (T1N * 4));           \
    } while (0)

#define LOADALL(P, KB) do {                                                 \
        LOAD1(P##0, KB, 0);   LOAD1(P##1, KB, 1);   LOAD1(P##2, KB, 2);     \
        LOAD1(P##3, KB, 3);   LOAD1(P##4, KB, 4);   LOAD1(P##5, KB, 5);     \
        LOAD1(P##6, KB, 6);   LOAD1(P##7, KB, 7);   LOAD1(P##8, KB, 8);     \
        LOAD1(P##9, KB, 9);   LOAD1(P##10, KB, 10); LOAD1(P##11, KB, 11);   \
        LOAD1(P##12, KB, 12); LOAD1(P##13, KB, 13); LOAD1(P##14, KB, 14);   \
        LOAD1(P##15, KB, 15);                                               \
    } while (0)

    // One DP step. Identical math to R18's proven step, with
    // fmin(x, fmin(y,z)+WP) == min3(x, y+WP, z+WP) (exact; monotone rounding).
#define DP_STEP(C4) do {                                                    \
        float4 c = (C4);                                                    \
        float p1 = SHFL_UP1(v1_3);                                          \
        float w0 = v1_0 + WPV, w1 = v1_1 + WPV;                             \
        float w2 = v1_2 + WPV, w3 = v1_3 + WPV;                             \
        float wp = p1 + WPV;                                                \
        float n0 = c.x + min3f(p1_prev, w0, wp);                            \
        float n1 = c.y + min3f(v2_0, w1, w0);                               \
        float n2 = c.z + min3f(v2_1, w2, w1);                               \
        float n3 = c.w + min3f(v2_2, w3, w2);                               \
        p1_prev = p1;                                                       \
        v2_0 = v1_0; v2_1 = v1_1; v2_2 = v1_2; v2_3 = v1_3;                 \
        v1_0 = n0;   v1_1 = n1;   v1_2 = n2;   v1_3 = n3;                   \
    } while (0)

#define DP_STEP_G(C4, R) do {                                               \
        float4 c = (C4);                                                    \
        float p1 = SHFL_UP1(v1_3);                                          \
        float w0 = v1_0 + WPV, w1 = v1_1 + WPV;                             \
        float w2 = v1_2 + WPV, w3 = v1_3 + WPV;                             \
        float wp = p1 + WPV;                                                \
        float n0 = c.x + min3f(p1_prev, w0, wp);                            \
        float n1 = c.y + min3f(v2_0, w1, w0);                               \
        float n2 = c.z + min3f(v2_1, w2, w1);                               \
        float n3 = c.w + min3f(v2_2, w3, w2);                               \
        if ((R) <= rem) {                                                   \
            p1_prev = p1;                                                   \
            v2_0 = v1_0; v2_1 = v1_1; v2_2 = v1_2; v2_3 = v1_3;             \
            v1_0 = n0;   v1_1 = n1;   v1_2 = n2;   v1_3 = n3;               \
        }                                                                   \
    } while (0)

    // consume row r of this block, immediately re-issue its load for blk+2
#define STEP_RL(C4, KB, R) do { DP_STEP(C4); LOAD1(C4, KB, R); } while (0)

#define PROC_RELOAD(P, KB) do {                                             \
        STEP_RL(P##0, KB, 0);   STEP_RL(P##1, KB, 1);                       \
        STEP_RL(P##2, KB, 2);   STEP_RL(P##3, KB, 3);                       \
        STEP_RL(P##4, KB, 4);   STEP_RL(P##5, KB, 5);                       \
        STEP_RL(P##6, KB, 6);   STEP_RL(P##7, KB, 7);                       \
        STEP_RL(P##8, KB, 8);   STEP_RL(P##9, KB, 9);                       \
        STEP_RL(P##10, KB, 10); STEP_RL(P##11, KB, 11);                     \
        STEP_RL(P##12, KB, 12); STEP_RL(P##13, KB, 13);                     \
        STEP_RL(P##14, KB, 14); STEP_RL(P##15, KB, 15);                     \
    } while (0)

#define PROC_FULL(P) do {                                                   \
        DP_STEP(P##0);  DP_STEP(P##1);  DP_STEP(P##2);  DP_STEP(P##3);      \
        DP_STEP(P##4);  DP_STEP(P##5);  DP_STEP(P##6);  DP_STEP(P##7);      \
        DP_STEP(P##8);  DP_STEP(P##9);  DP_STEP(P##10); DP_STEP(P##11);     \
        DP_STEP(P##12); DP_STEP(P##13); DP_STEP(P##14); DP_STEP(P##15);     \
    } while (0)

#define PROC_GUARD(P) do {                                                  \
        DP_STEP_G(P##0, 0);   DP_STEP_G(P##1, 1);   DP_STEP_G(P##2, 2);     \
        DP_STEP_G(P##3, 3);   DP_STEP_G(P##4, 4);   DP_STEP_G(P##5, 5);     \
        DP_STEP_G(P##6, 6);   DP_STEP_G(P##7, 7);   DP_STEP_G(P##8, 8);     \
        DP_STEP_G(P##9, 9);   DP_STEP_G(P##10, 10); DP_STEP_G(P##11, 11);   \
        DP_STEP_G(P##12, 12); DP_STEP_G(P##13, 13); DP_STEP_G(P##14, 14);   \
        DP_STEP_G(P##15, 15);                                               \
    } while (0)

    // prologue: blocks 0 and 1 in flight
    LOADALL(A, 0);
    LOADALL(B, 1);

    // kLast in [39,79] so the pair loop always runs
    int k = 0;
    while (k + 1 < kLast) {               // blocks k, k+1 are full
        PROC_RELOAD(A, k + 2);
        PROC_RELOAD(B, k + 3);
        k += 2;
    }
    if (k < kLast) {                      // k == kLast-1: full A, guarded B
        PROC_FULL(A);
        const int rem = dEnd & 15;
        PROC_GUARD(B);
    } else {                              // k == kLast: guarded A
        const int rem = dEnd & 15;
        PROC_GUARD(A);
    }

    // publish partials[b] with a replay-safe magic flag (poison-robust store)
    const int tcap = la - 1;
    if (L == (tcap >> 2)) {
        const int kk = tcap & 3;
        float r = v1_0;
        if (kk == 1) r = v1_1;
        else if (kk == 2) r = v1_2;
        else if (kk == 3) r = v1_3;
        partials[b] = r;
        __threadfence();
        __hip_atomic_store(&flags[b], FLAG_MAGIC + b,
                           __ATOMIC_RELEASE, __HIP_MEMORY_SCOPE_AGENT);
    }

    // block 0: gather all 8 partials and write the final sum
    if (b == 0 && L == 0) {
        float s = 0.0f;
        for (int i = 0; i < BATCH; ++i) {
            while (__hip_atomic_load(&flags[i], __ATOMIC_ACQUIRE,
                                     __HIP_MEMORY_SCOPE_AGENT) != FLAG_MAGIC + i)
                __builtin_amdgcn_s_sleep(2);
            s += __hip_atomic_load(&partials[i], __ATOMIC_RELAXED,
                                   __HIP_MEMORY_SCOPE_AGENT);
        }
        out[0] = s;
    }
#undef PROC_GUARD
#undef PROC_FULL
#undef PROC_RELOAD
#undef STEP_RL
#undef DP_STEP_G
#undef DP_STEP
#undef LOADALL
#undef LOAD1
#undef SHFL_UP1
}

extern "C" void kernel_launch(void* const* d_in, const int* in_sizes, int n_in,
                              void* d_out, int out_size, void* d_ws, size_t ws_size,
                              hipStream_t stream) {
    const float* feaA = (const float*)d_in[0];
    const int*   lenA = (const int*)d_in[1];
    const float* feaB = (const float*)d_in[2];
    const int*   lenB = (const int*)d_in[3];

    float* sk = (float*)d_ws;                                   // 8*1279*256*4 B
    float* partials = (float*)((char*)d_ws + (size_t)BATCH * DN * T1N * sizeof(float));
    int*   flags    = (int*)(partials + BATCH);

    cost_kernel<<<dim3(T1N / 64, (DN + 31) / 32, BATCH), 256, 0, stream>>>(feaA, feaB, lenA, lenB, sk);
    dp_reg_kernel<<<BATCH, 64, 0, stream>>>(sk, lenA, lenB, partials, flags, (float*)d_out);
}